// Round 4
// baseline (240.181 us; speedup 1.0000x reference)
//
#include <hip/hip_runtime.h>

// DilateAttention: B=4, d=384 (12 heads x 32), H=W=64, 3x3 taps, dilation 2, pad 2.
// f32 in / f32 out.
// v5: tap-split. Evidence from v1-v4:
//   - WRITE amp is clean ONLY when one lane writes a pixel-head's 128 B
//     contiguously (v1: 1.3x; any lane-split of the 128 B: 5.7-9.7x).
//   - FETCH is clean ONLY with XCD swizzle putting y-adjacent blocks on the
//     same XCD L2 (v3: 95 MB; v4 no-swizzle: 3x refetch of k/v = 259 MB).
//   - v1's limit was concurrency (12 waves/CU, latency-bound at 2 TB/s).
// => split TAPS (not channels) across 2 threads/pixel: both keep all 32 ch,
//    tg0 owns taps 0-4, tg1 owns taps 5-8 (+1 dummy). Partial logits and
//    partial o[32] exchanged in-wave via shfl_xor(32). Only tg0 stores
//    (v1's exact per-lane 128-B pattern). 6144 waves = 24/CU.

#define NHD  12
#define DDIM 384
#define HH   64
#define WW   64
#define HWSZ 4096
#define SCALEF 0.17677669529663687f  // 1/sqrt(32)

// block = 256 = 4 waves; wave = 32 pixels x 2 tap-groups (tg = lane bit 5).
// block covers 2 rows. grid = B*NH*(H/2) = 1536 = 8 XCDs x 192.
__global__ __launch_bounds__(256, 6) void dilate_attn(const float* __restrict__ q,
                                                      const float* __restrict__ k,
                                                      const float* __restrict__ v,
                                                      float* __restrict__ out) {
    const int tid = threadIdx.x;
    const int xi  = tid & 31;            // pixel x within half-row
    const int tg  = (tid >> 5) & 1;      // tap group, lane bit 5
    const int xh  = (tid >> 6) & 1;      // which half-row
    const int r   = tid >> 7;            // row within block
    const int x   = xh * 32 + xi;

    // XCD swizzle: contiguous 192-logical-block chunk per XCD (bijective).
    const int phys = blockIdx.x;
    const int bz   = (phys & 7) * 192 + (phys >> 3);

    const int y  = (bz & 31) * 2 + r;
    const int bh = bz >> 5;              // b*NH + n
    const int b  = bh / NHD;
    const int n  = bh - b * NHD;

    const int cbase = (b * DDIM + n * 32) * HWSZ;
    const int pix   = y * WW + x;

    // Own taps: global tap id t = tg*5 + lt (t=9 is tg1's dummy, always invalid).
    int  toff[5];
    bool tvo[5];
#pragma unroll
    for (int lt = 0; lt < 5; ++lt) {
        int t  = tg * 5 + lt;            // 0..9
        int di = t / 3;                  // small runtime div, cheap
        int p  = t - 3 * di;
        int yy = y + 2 * di - 2;
        int xo = x + 2 * p - 2;
        bool ok = (t < 9) && (yy >= 0) && (yy < HH) && (xo >= 0) && (xo < WW);
        tvo[lt]  = ok;
        toff[lt] = ok ? (yy * WW + xo) : pix;   // clamped: always in-bounds
    }

    // ---------------- preload q (scale folded in): all 32 channels ----------
    float qreg[32];
#pragma unroll
    for (int c = 0; c < 32; ++c) qreg[c] = q[cbase + pix + c * HWSZ] * SCALEF;

    // ---------------- Phase 1: 5 own logits over 32 channels ----------------
    float lp[5];
#pragma unroll
    for (int lt = 0; lt < 5; ++lt) {
        const int kb = cbase + toff[lt];
        float a0 = 0.f, a1 = 0.f;
#pragma unroll
        for (int c = 0; c < 32; c += 2) {
            a0 += qreg[c]     * k[kb + c * HWSZ];
            a1 += qreg[c + 1] * k[kb + (c + 1) * HWSZ];
        }
        lp[lt] = tvo[lt] ? (a0 + a1) : 0.f;  // invalid/dummy taps: logit 0
    }

    // ---- exchange partial logits with partner (lane xi^32, other tg) -------
    float rp[5];
#pragma unroll
    for (int lt = 0; lt < 5; ++lt) rp[lt] = __shfl_xor(lp[lt], 32, 64);

    float l9[9];
#pragma unroll
    for (int j = 0; j < 5; ++j) l9[j] = tg ? rp[j] : lp[j];
#pragma unroll
    for (int j = 0; j < 4; ++j) l9[5 + j] = tg ? lp[j] : rp[j];

    // ---------------- Softmax over 9 ----------------------------------------
    float m = l9[0];
#pragma unroll
    for (int t = 1; t < 9; ++t) m = fmaxf(m, l9[t]);
    float w[9], s = 0.f;
#pragma unroll
    for (int t = 0; t < 9; ++t) { w[t] = __expf(l9[t] - m); s += w[t]; }
    float inv = 1.0f / s;

    // Own weights (static indexing only; gate invalid/dummy with tvo).
    float ow[5];
#pragma unroll
    for (int lt = 0; lt < 5; ++lt) {
        float wl = w[lt];
        float wh = (lt < 4) ? w[5 + lt] : 0.f;
        ow[lt] = tvo[lt] ? ((tg ? wh : wl) * inv) : 0.f;   // padded V == 0
    }

    // ---------------- Phase 2: weighted V over own 5 taps, 32 channels ------
    float o[32];
#pragma unroll
    for (int c = 0; c < 32; ++c) o[c] = 0.f;
#pragma unroll
    for (int lt = 0; lt < 5; ++lt) {
        const int vb = cbase + toff[lt];
        float wt = ow[lt];
#pragma unroll
        for (int c = 0; c < 32; ++c) o[c] += wt * v[vb + c * HWSZ];
    }

    // ---- sum partner's partial o -------------------------------------------
#pragma unroll
    for (int c = 0; c < 32; ++c) o[c] += __shfl_xor(o[c], 32, 64);

    // ---------------- Output: tg0 lane writes the full 128-B head chunk -----
    if (tg == 0) {
        const int ob = (b * HH * WW + pix) * DDIM + n * 32;
#pragma unroll
        for (int j = 0; j < 8; ++j)
            *(float4*)(out + ob + j * 4) =
                make_float4(o[j * 4], o[j * 4 + 1], o[j * 4 + 2], o[j * 4 + 3]);
    }
}

extern "C" void kernel_launch(void* const* d_in, const int* in_sizes, int n_in,
                              void* d_out, int out_size, void* d_ws, size_t ws_size,
                              hipStream_t stream) {
    const float* q = (const float*)d_in[0];
    const float* k = (const float*)d_in[1];
    const float* v = (const float*)d_in[2];
    float* out = (float*)d_out;
    hipLaunchKernelGGL(dilate_attn, dim3(1536), dim3(256), 0, stream, q, k, v, out);
}

// Round 5
// 235.229 us; speedup vs baseline: 1.0211x; 1.0211x over previous
//
#include <hip/hip_runtime.h>

// DilateAttention: B=4, d=384 (12 heads x 32), H=W=64, 3x3 taps, dilation 2, pad 2.
// f32 in / f32 out.
// v6: v1's traffic-clean geometry (4-row blocks, grid 768, no swizzle, per-lane
// 128-B output) + LDS staging of k/v to kill the latency wall.
// Evidence v1-v5: only 4-row blocks keep L2 clean (FETCH 60 MB < 75.5 read-once
// floor; 1-2-row variants: 203-259 MB fetch AND 140-276 MB write via L2 thrash).
// v1's 47 us = 610 scattered 4-B loads/thread in ~13 reg-limited latency batches.
// v6 stages the block footprint (8 rows x 64 x x 32 ch, two 16-ch chunks) in
// 34.8 KB LDS via dense float4 copies: 64 global load instrs/thread (10x fewer),
// issue-early/write-late (T14) so HBM latency hides under compute; tap dots read
// LDS (lane-consecutive x = conflict-free; row stride 68 words = bank-uniform,
// 16-B-aligned b128 staging writes).

#define NHD  12
#define DDIM 384
#define HH   64
#define WW   64
#define HWSZ 4096
#define SCALEF 0.17677669529663687f  // 1/sqrt(32)
#define RSTR 68                      // LDS row stride (words): uniform b128 banks
#define CSTR 544                     // LDS channel stride = 8*RSTR
// LDS total: 16 ch x 544 words x 4 B = 34816 B

// block = 256 = 4 waves, wave = one row of 64 x. grid = B*NH*(H/4) = 768.
__global__ __launch_bounds__(256, 3) void dilate_attn(const float* __restrict__ q,
                                                      const float* __restrict__ k,
                                                      const float* __restrict__ v,
                                                      float* __restrict__ out) {
    __shared__ float smem[16 * CSTR];

    const int tid = threadIdx.x;
    const int x   = tid & 63;
    const int r   = tid >> 6;            // row within block
    const int bz  = blockIdx.x;          // no swizzle (v1-proven clean)
    const int bh  = bz >> 4;             // b*NH + n
    const int y0  = (bz & 15) * 4;
    const int y   = y0 + r;
    const int b   = bh / NHD;
    const int n   = bh - b * NHD;

    const int cbase = (b * DDIM + n * 32) * HWSZ;
    const int pix   = y * WW + x;

    // ---- staging map: 256 threads x 8 iters cover 16 ch x 8 rows x 16 quads
    const int s_ro = (tid >> 4) & 7;
    const int s_x4 = (tid & 15) * 4;
    const int s_ch = tid >> 7;           // chunk channel = 2*i + s_ch
    int syy = y0 - 2 + s_ro;             // clamped halo row (gated later)
    syy = syy < 0 ? 0 : (syy > 63 ? 63 : syy);
    const int s_goff = syy * WW + s_x4;                    // + ch*HWSZ
    const int s_loff = s_ch * CSTR + s_ro * RSTR + s_x4;   // + 2i*CSTR

    // ---- tap validity + clamped x offsets
    bool tval[9];
#pragma unroll
    for (int di = 0; di < 3; ++di) {
        int yy = y + 2 * di - 2;
        bool vy = (yy >= 0) && (yy < HH);
#pragma unroll
        for (int p = 0; p < 3; ++p) {
            int xo = x + 2 * p - 2;
            tval[di * 3 + p] = vy && (xo >= 0) && (xo < WW);
        }
    }
    int xc[3];
#pragma unroll
    for (int p = 0; p < 3; ++p) {
        int xo = x + 2 * p - 2;
        xc[p] = xo < 0 ? 0 : (xo > 63 ? 63 : xo);
    }

    // ================= stage k ch 0-15: issue loads =================
    float4 tmp[8];
    const float* kb = k + cbase;
#pragma unroll
    for (int i = 0; i < 8; ++i)
        tmp[i] = *(const float4*)(kb + (2 * i + s_ch) * HWSZ + s_goff);

    // q preload (scale folded), overlaps the staging loads
    float qreg[32];
#pragma unroll
    for (int c = 0; c < 32; ++c) qreg[c] = q[cbase + c * HWSZ + pix] * SCALEF;

#pragma unroll
    for (int i = 0; i < 8; ++i)
        *(float4*)(&smem[2 * i * CSTR + s_loff]) = tmp[i];
    __syncthreads();

    // prefetch k ch 16-31 (hides under logits-lo compute)
    const float* kb2 = kb + 16 * HWSZ;
#pragma unroll
    for (int i = 0; i < 8; ++i)
        tmp[i] = *(const float4*)(kb2 + (2 * i + s_ch) * HWSZ + s_goff);

    // ---------------- logits from ch 0-15 ----------------
    float l[9];
#pragma unroll
    for (int t = 0; t < 9; ++t) l[t] = 0.f;
#pragma unroll
    for (int di = 0; di < 3; ++di) {
        const int rb = (r + 2 * di) * RSTR;
#pragma unroll
        for (int p = 0; p < 3; ++p) {
            const int base = rb + xc[p];
            float a0 = 0.f, a1 = 0.f;
#pragma unroll
            for (int c = 0; c < 16; c += 2) {
                a0 += qreg[c]     * smem[c * CSTR + base];
                a1 += qreg[c + 1] * smem[(c + 1) * CSTR + base];
            }
            l[di * 3 + p] += a0 + a1;
        }
    }
    __syncthreads();                      // readers done with k-lo
#pragma unroll
    for (int i = 0; i < 8; ++i)
        *(float4*)(&smem[2 * i * CSTR + s_loff]) = tmp[i];
    __syncthreads();

    // prefetch v ch 0-15 (hides under logits-hi + softmax)
    const float* vb = v + cbase;
#pragma unroll
    for (int i = 0; i < 8; ++i)
        tmp[i] = *(const float4*)(vb + (2 * i + s_ch) * HWSZ + s_goff);

    // ---------------- logits from ch 16-31 ----------------
#pragma unroll
    for (int di = 0; di < 3; ++di) {
        const int rb = (r + 2 * di) * RSTR;
#pragma unroll
        for (int p = 0; p < 3; ++p) {
            const int base = rb + xc[p];
            float a0 = 0.f, a1 = 0.f;
#pragma unroll
            for (int c = 0; c < 16; c += 2) {
                a0 += qreg[16 + c] * smem[c * CSTR + base];
                a1 += qreg[17 + c] * smem[(c + 1) * CSTR + base];
            }
            l[di * 3 + p] += a0 + a1;
        }
    }

    // ---------------- softmax over 9 (zero-pad taps -> logit 0) -------------
    float w[9];
#pragma unroll
    for (int t = 0; t < 9; ++t) l[t] = tval[t] ? l[t] : 0.f;
    float m = l[0];
#pragma unroll
    for (int t = 1; t < 9; ++t) m = fmaxf(m, l[t]);
    float s = 0.f;
#pragma unroll
    for (int t = 0; t < 9; ++t) { w[t] = __expf(l[t] - m); s += w[t]; }
    float inv = 1.0f / s;
#pragma unroll
    for (int t = 0; t < 9; ++t) w[t] = tval[t] ? (w[t] * inv) : 0.f;  // padded V == 0

    __syncthreads();                      // readers done with k-hi
#pragma unroll
    for (int i = 0; i < 8; ++i)
        *(float4*)(&smem[2 * i * CSTR + s_loff]) = tmp[i];
    __syncthreads();

    // prefetch v ch 16-31 (hides under o-lo compute)
    const float* vb2 = vb + 16 * HWSZ;
#pragma unroll
    for (int i = 0; i < 8; ++i)
        tmp[i] = *(const float4*)(vb2 + (2 * i + s_ch) * HWSZ + s_goff);

    // ---------------- o ch 0-15 + store first 64 B ----------------
    const int ob = (b * HH * WW + pix) * DDIM + n * 32;
    float o[16];
#pragma unroll
    for (int c = 0; c < 16; ++c) o[c] = 0.f;
#pragma unroll
    for (int di = 0; di < 3; ++di) {
        const int rb = (r + 2 * di) * RSTR;
#pragma unroll
        for (int p = 0; p < 3; ++p) {
            const float wt = w[di * 3 + p];
            const int base = rb + xc[p];
#pragma unroll
            for (int c = 0; c < 16; ++c) o[c] += wt * smem[c * CSTR + base];
        }
    }
#pragma unroll
    for (int j = 0; j < 4; ++j)
        *(float4*)(out + ob + j * 4) =
            make_float4(o[j * 4], o[j * 4 + 1], o[j * 4 + 2], o[j * 4 + 3]);

    __syncthreads();                      // readers done with v-lo
#pragma unroll
    for (int i = 0; i < 8; ++i)
        *(float4*)(&smem[2 * i * CSTR + s_loff]) = tmp[i];
    __syncthreads();

    // ---------------- o ch 16-31 + store second 64 B ----------------
#pragma unroll
    for (int c = 0; c < 16; ++c) o[c] = 0.f;
#pragma unroll
    for (int di = 0; di < 3; ++di) {
        const int rb = (r + 2 * di) * RSTR;
#pragma unroll
        for (int p = 0; p < 3; ++p) {
            const float wt = w[di * 3 + p];
            const int base = rb + xc[p];
#pragma unroll
            for (int c = 0; c < 16; ++c) o[c] += wt * smem[c * CSTR + base];
        }
    }
#pragma unroll
    for (int j = 0; j < 4; ++j)
        *(float4*)(out + ob + 16 + j * 4) =
            make_float4(o[j * 4], o[j * 4 + 1], o[j * 4 + 2], o[j * 4 + 3]);
}

extern "C" void kernel_launch(void* const* d_in, const int* in_sizes, int n_in,
                              void* d_out, int out_size, void* d_ws, size_t ws_size,
                              hipStream_t stream) {
    const float* q = (const float*)d_in[0];
    const float* k = (const float*)d_in[1];
    const float* v = (const float*)d_in[2];
    float* out = (float*)d_out;
    hipLaunchKernelGGL(dilate_attn, dim3(768), dim3(256), 0, stream, q, k, v, out);
}

// Round 6
// 157.023 us; speedup vs baseline: 1.5296x; 1.4981x over previous
//
#include <hip/hip_runtime.h>

// DilateAttention: B=4, d=384 (12 heads x 32), H=W=64, 3x3 taps, dilation 2, pad 2.
// f32 in / f32 out.
// v7: v1 with in-thread ILP restructure ONLY. Lessons v1-v6: v1's geometry
// (1 px/thread, 4-row blocks, grid 768, no swizzle, per-lane 128-B stores) is
// the only traffic-clean config; every geometry change (channel-split waves,
// tap-split, 2-row blocks, swizzle, LDS staging) regressed 2-5x. v1's real
// limit: source interleaves each scattered load with a dependent FMA -> only
// ~35 loads in flight (VGPR 104), ~16 exposed-latency batches/wave, 3
// waves/SIMD can't cover them (VALUBusy 15%, 1 VMEM issued/15 cy/CU).
// v7: load-then-compute in 3-tap batches (96 independent loads into a reg
// array before any FMA) for both QK and PV. Outstanding loads ~3x, exposed
// batches ~6. launch_bounds(256,3) caps VGPR at 170 so 3 blocks/CU hold.

#define NHD  12
#define DDIM 384
#define HH   64
#define WW   64
#define HWSZ 4096
#define SCALEF 0.17677669529663687f  // 1/sqrt(32)

// block = 256: 4 y-rows x 64 x-lanes. grid = B*NH*(H/4) = 768.
__global__ __launch_bounds__(256, 3) void dilate_attn(const float* __restrict__ q,
                                                      const float* __restrict__ k,
                                                      const float* __restrict__ v,
                                                      float* __restrict__ out) {
    const int tid = threadIdx.x;
    const int r   = tid >> 6;          // 0..3
    const int x   = tid & 63;
    const int bz  = blockIdx.x;
    const int bh  = bz >> 4;           // b*NH + n
    const int b   = bh / NHD;
    const int n   = bh - b * NHD;
    const int y   = (bz & 15) * 4 + r;

    const int cbase = (b * DDIM + n * 32) * HWSZ;   // 32-bit indexing (max ~6M)
    const int pix   = y * WW + x;

    // 9 tap offsets, clamped to center when OOB; validity recorded separately.
    int  toff[9];
    bool tval[9];
#pragma unroll
    for (int di = 0; di < 3; ++di) {
        int yy = y + 2 * di - 2;
        bool vy = (yy >= 0) && (yy < HH);
#pragma unroll
        for (int p = 0; p < 3; ++p) {
            int xo = x + 2 * p - 2;
            bool ok = vy && (xo >= 0) && (xo < WW);
            tval[di * 3 + p] = ok;
            toff[di * 3 + p] = ok ? (yy * WW + xo) : pix;   // clamped: in-bounds
        }
    }

    // ---------------- preload q (scale folded in) ----------------
    float qreg[32];
#pragma unroll
    for (int c = 0; c < 32; ++c) qreg[c] = q[cbase + pix + c * HWSZ] * SCALEF;

    // ---------------- Phase 1: logits, 3 batches of (3 taps x 32 ch) --------
    // All 96 loads of a batch are issued before any FMA consumes them.
    float l[9];
#pragma unroll
    for (int g = 0; g < 3; ++g) {
        float kv[3][32];
#pragma unroll
        for (int j = 0; j < 3; ++j) {
            const int kb = cbase + toff[g * 3 + j];
#pragma unroll
            for (int c = 0; c < 32; ++c) kv[j][c] = k[kb + c * HWSZ];
        }
#pragma unroll
        for (int j = 0; j < 3; ++j) {
            float a0 = 0.f, a1 = 0.f;
#pragma unroll
            for (int c = 0; c < 32; c += 2) {
                a0 += qreg[c]     * kv[j][c];
                a1 += qreg[c + 1] * kv[j][c + 1];
            }
            l[g * 3 + j] = tval[g * 3 + j] ? (a0 + a1) : 0.f;  // zero-pad: logit 0
        }
    }

    // ---------------- Softmax over 9 ----------------
    float m = l[0];
#pragma unroll
    for (int t = 1; t < 9; ++t) m = fmaxf(m, l[t]);
    float w[9], s = 0.f;
#pragma unroll
    for (int t = 0; t < 9; ++t) { w[t] = __expf(l[t] - m); s += w[t]; }
    float inv = 1.0f / s;
#pragma unroll
    for (int t = 0; t < 9; ++t) w[t] = tval[t] ? (w[t] * inv) : 0.f;  // padded V == 0

    // ---------------- Phase 2: weighted V, 3 batches of (3 taps x 32 ch) ----
    float o[32];
#pragma unroll
    for (int c = 0; c < 32; ++c) o[c] = 0.f;
#pragma unroll
    for (int g = 0; g < 3; ++g) {
        float vv[3][32];
#pragma unroll
        for (int j = 0; j < 3; ++j) {
            const int vb = cbase + toff[g * 3 + j];
#pragma unroll
            for (int c = 0; c < 32; ++c) vv[j][c] = v[vb + c * HWSZ];
        }
#pragma unroll
        for (int j = 0; j < 3; ++j) {
            const float wt = w[g * 3 + j];
#pragma unroll
            for (int c = 0; c < 32; ++c) o[c] += wt * vv[j][c];
        }
    }

    // ---------------- Output: lane owns the full 128-B head chunk -----------
    const int ob = (b * HH * WW + pix) * DDIM + n * 32;
#pragma unroll
    for (int j = 0; j < 8; ++j)
        *(float4*)(out + ob + j * 4) =
            make_float4(o[j * 4], o[j * 4 + 1], o[j * 4 + 2], o[j * 4 + 3]);
}

extern "C" void kernel_launch(void* const* d_in, const int* in_sizes, int n_in,
                              void* d_out, int out_size, void* d_ws, size_t ws_size,
                              hipStream_t stream) {
    const float* q = (const float*)d_in[0];
    const float* k = (const float*)d_in[1];
    const float* v = (const float*)d_in[2];
    float* out = (float*)d_out;
    hipLaunchKernelGGL(dilate_attn, dim3(768), dim3(256), 0, stream, q, k, v, out);
}